// Round 2
// baseline (2161.954 us; speedup 1.0000x reference)
//
#include <hip/hip_runtime.h>
#include <math.h>

// Problem constants
#define B_    256
#define N_    128
#define F_    133
#define H_    8
#define ND_   64     // NHID
#define HID_  300
#define FPD_  1489
#define FP2_  512
#define ALPHA_ 0.2f
#define NEG_  -9.0e15f

__device__ __forceinline__ float wred_sum(float v) {
#pragma unroll
  for (int m = 32; m >= 1; m >>= 1) v += __shfl_xor(v, m, 64);
  return v;
}
__device__ __forceinline__ float wred_max(float v) {
#pragma unroll
  for (int m = 32; m >= 1; m >>= 1) v = fmaxf(v, __shfl_xor(v, m, 64));
  return v;
}
__device__ __forceinline__ float lrelu(float x) { return x > 0.f ? x : ALPHA_ * x; }
__device__ __forceinline__ float eluf(float x)  { return x > 0.f ? x : expf(x) - 1.f; }
__device__ __forceinline__ float rdlane(float v, int l) {
  return __int_as_float(__builtin_amdgcn_readlane(__float_as_int(v), l));
}

// K1: Wh[b,h,n,d] = sum_f A[b,n,f] * W[h,f,d];  s/d head projections fused.
// grid (2048, 8), block 64 (1 wave, lane = d). 16 rows per block.
__global__ __launch_bounds__(64) void k1_wh(
    const float* __restrict__ A, const float* __restrict__ W,
    const float* __restrict__ ah, float* __restrict__ Wh,
    float* __restrict__ sb, float* __restrict__ db) {
  const int lane = threadIdx.x;
  const int h = blockIdx.y;
  const int m0 = blockIdx.x * 16;           // flat row b*N+n
  const float* Wg = W + (size_t)h * F_ * ND_;
  float acc[16];
#pragma unroll
  for (int r = 0; r < 16; ++r) acc[r] = 0.f;
  for (int f = 0; f < F_; ++f) {
    float wv = Wg[f * ND_ + lane];
#pragma unroll
    for (int r = 0; r < 16; ++r)
      acc[r] = fmaf(A[(size_t)(m0 + r) * F_ + f], wv, acc[r]);
  }
  float a1 = ah[h * 2 * ND_ + lane];
  float a2 = ah[h * 2 * ND_ + ND_ + lane];
  const int b = m0 >> 7, n0 = m0 & (N_ - 1);
  const size_t bh = (size_t)b * H_ + h;
#pragma unroll
  for (int r = 0; r < 16; ++r) {
    Wh[(bh * N_ + n0 + r) * ND_ + lane] = acc[r];
    float sv = wred_sum(acc[r] * a1);
    float dv = wred_sum(acc[r] * a2);
    if (lane == 0) {
      sb[bh * N_ + n0 + r] = sv;
      db[bh * N_ + n0 + r] = dv;
    }
  }
}

// K2: masked softmax over j + h = elu(attn @ Wh), written as hbuf[b,i,h*64+d].
// grid 8192, block 256 (4 waves); each wave owns 8 rows of one (b,h).
__global__ __launch_bounds__(256) void k2_attn1(
    const float* __restrict__ Wh, const float* __restrict__ sb,
    const float* __restrict__ db, const int* __restrict__ adj,
    float* __restrict__ hb) {
  const int lane = threadIdx.x & 63;
  const int w = blockIdx.x * 4 + (threadIdx.x >> 6);  // 0..32767
  const int bh = w >> 4;
  const int i0 = (w & 15) * 8;
  const int b = bh >> 3, h = bh & 7;
  const float* dbase = db + (size_t)bh * N_;
  const float dv0 = dbase[lane], dv1 = dbase[64 + lane];
  float p0[8], p1[8];
#pragma unroll
  for (int r = 0; r < 8; ++r) {
    const int i = i0 + r;
    float sv = sb[(size_t)bh * N_ + i];
    const int* arow = adj + ((size_t)b * N_ + i) * N_;
    int a0 = arow[lane], a1i = arow[64 + lane];
    float e0 = a0 > 0 ? lrelu(sv + dv0) : NEG_;
    float e1 = a1i > 0 ? lrelu(sv + dv1) : NEG_;
    float mx = wred_max(fmaxf(e0, e1));
    float x0 = expf(e0 - mx), x1 = expf(e1 - mx);
    float inv = 1.f / wred_sum(x0 + x1);
    p0[r] = x0 * inv;
    p1[r] = x1 * inv;
  }
  const float* whb = Wh + (size_t)bh * N_ * ND_ + lane;
  float acc[8];
#pragma unroll
  for (int r = 0; r < 8; ++r) acc[r] = 0.f;
  for (int j = 0; j < 64; ++j) {
    float wv = whb[(size_t)j * ND_];
#pragma unroll
    for (int r = 0; r < 8; ++r) acc[r] = fmaf(rdlane(p0[r], j), wv, acc[r]);
  }
  for (int j = 0; j < 64; ++j) {
    float wv = whb[(size_t)(64 + j) * ND_];
#pragma unroll
    for (int r = 0; r < 8; ++r) acc[r] = fmaf(rdlane(p1[r], j), wv, acc[r]);
  }
  float* hrow = hb + ((size_t)b * N_ + i0) * (H_ * ND_) + h * ND_ + lane;
#pragma unroll
  for (int r = 0; r < 8; ++r) hrow[(size_t)r * (H_ * ND_)] = eluf(acc[r]);
}

// Generic GEMM: C[m, c] = act(sum_k A[m,k]*B[k,c] + bias[c]).
// A accesses are wave-uniform -> scalar loads. One column per thread,
// ROWS rows register-blocked. act: 0 none, 1 relu.
template <int ROWS>
__global__ void gemm_sA(const float* __restrict__ A, const float* __restrict__ Bm,
                        const float* __restrict__ bias, float* __restrict__ C,
                        int K, int N, int ldc, int act) {
  const int c = threadIdx.x;
  const int r0 = blockIdx.x * ROWS;
  if (c >= N) return;
  float acc[ROWS];
#pragma unroll
  for (int r = 0; r < ROWS; ++r) acc[r] = bias ? bias[c] : 0.f;
  for (int k = 0; k < K; ++k) {
    float bv = Bm[(size_t)k * N + c];
#pragma unroll
    for (int r = 0; r < ROWS; ++r)
      acc[r] = fmaf(A[(size_t)(r0 + r) * K + k], bv, acc[r]);
  }
#pragma unroll
  for (int r = 0; r < ROWS; ++r) {
    float v = acc[r];
    if (act == 1) v = fmaxf(v, 0.f);
    C[(size_t)(r0 + r) * ldc + c] = v;
  }
}

// K4: s2/d2 = Wh2 @ a_out halves. One wave per row.
__global__ __launch_bounds__(256) void k4_sd2(
    const float* __restrict__ Wh2, const float* __restrict__ ao,
    float* __restrict__ s2, float* __restrict__ d2) {
  const int lane = threadIdx.x & 63;
  const int row = blockIdx.x * 4 + (threadIdx.x >> 6);
  const float* wrow = Wh2 + (size_t)row * HID_;
  float as = 0.f, ad = 0.f;
  for (int c = lane; c < HID_; c += 64) {
    float v = wrow[c];
    as = fmaf(v, ao[c], as);
    ad = fmaf(v, ao[HID_ + c], ad);
  }
  as = wred_sum(as);
  ad = wred_sum(ad);
  if (lane == 0) { s2[row] = as; d2[row] = ad; }
}

// K5: attn2 probabilities p2[b,i,j]. One wave per row i.
__global__ __launch_bounds__(256) void k5_p2(
    const float* __restrict__ s2, const float* __restrict__ d2,
    const int* __restrict__ adj, float* __restrict__ p2) {
  const int lane = threadIdx.x & 63;
  const int row = blockIdx.x * 4 + (threadIdx.x >> 6);  // b*N+i
  const int b = row >> 7;
  float sv = s2[row];
  const float* drow = d2 + (size_t)b * N_;
  const int* arow = adj + (size_t)row * N_;
  float dv0 = drow[lane], dv1 = drow[64 + lane];
  int a0 = arow[lane], a1i = arow[64 + lane];
  float e0 = a0 > 0 ? lrelu(sv + dv0) : NEG_;
  float e1 = a1i > 0 ? lrelu(sv + dv1) : NEG_;
  float mx = wred_max(fmaxf(e0, e1));
  float x0 = expf(e0 - mx), x1 = expf(e1 - mx);
  float inv = 1.f / wred_sum(x0 + x1);
  p2[(size_t)row * N_ + lane] = x0 * inv;
  p2[(size_t)row * N_ + 64 + lane] = x1 * inv;
}

// K6: obuf = elu(p2 @ Wh2), batched per b. grid 2048, block 320.
__global__ void k6_out(const float* __restrict__ p2, const float* __restrict__ Wh2,
                       float* __restrict__ ob) {
  const int c = threadIdx.x;
  const int r0 = blockIdx.x * 16;  // flat row b*N+n
  const int b = r0 >> 7;
  if (c >= HID_) return;
  float acc[16];
#pragma unroll
  for (int r = 0; r < 16; ++r) acc[r] = 0.f;
  const float* wb = Wh2 + (size_t)b * N_ * HID_ + c;
  for (int j = 0; j < N_; ++j) {
    float bv = wb[(size_t)j * HID_];
#pragma unroll
    for (int r = 0; r < 16; ++r)
      acc[r] = fmaf(p2[(size_t)(r0 + r) * N_ + j], bv, acc[r]);
  }
#pragma unroll
  for (int r = 0; r < 16; ++r)
    ob[(size_t)(r0 + r) * HID_ + c] = eluf(acc[r]);
}

// K7: per-row max and log-sum-exp over 300 cols. One wave per row.
__global__ __launch_bounds__(256) void k7_lse(
    const float* __restrict__ ob, float* __restrict__ mx, float* __restrict__ ls) {
  const int lane = threadIdx.x & 63;
  const int row = blockIdx.x * 4 + (threadIdx.x >> 6);
  const float* orow = ob + (size_t)row * HID_;
  float v[5], m = -1e30f;
#pragma unroll
  for (int q = 0; q < 5; ++q) {
    int c = lane + q * 64;
    v[q] = (c < HID_) ? orow[c] : -1e30f;
    m = fmaxf(m, v[q]);
  }
  m = wred_max(m);
  float s = 0.f;
#pragma unroll
  for (int q = 0; q < 5; ++q) {
    int c = lane + q * 64;
    if (c < HID_) s += expf(v[q] - m);
  }
  s = wred_sum(s);
  if (lane == 0) { mx[row] = m; ls[row] = logf(s); }
}

// K8: gat_out[b,c] = mean_i (ob[b,i,c] - mx - ls). grid 256, block 320.
__global__ void k8_mean(const float* __restrict__ ob, const float* __restrict__ mx,
                        const float* __restrict__ ls, float* __restrict__ gat) {
  const int c = threadIdx.x;
  const int b = blockIdx.x;
  if (c >= HID_) return;
  float acc = 0.f;
  for (int i = 0; i < N_; ++i) {
    int row = b * N_ + i;
    acc += ob[(size_t)row * HID_ + c] - mx[row] - ls[row];
  }
  gat[(size_t)b * HID_ + c] = acc * (1.f / N_);
}

// K12b: out[b] = sigmoid(y[b,:] @ ffn_w2 + b2). One wave per row.
__global__ __launch_bounds__(256) void k_final(
    const float* __restrict__ y, const float* __restrict__ w2,
    const float* __restrict__ b2, float* __restrict__ out) {
  const int lane = threadIdx.x & 63;
  const int b = blockIdx.x * 4 + (threadIdx.x >> 6);
  float acc = 0.f;
  for (int c = lane; c < HID_; c += 64)
    acc = fmaf(y[(size_t)b * HID_ + c], w2[c], acc);
  acc = wred_sum(acc);
  if (lane == 0) out[b] = 1.f / (1.f + expf(-(acc + b2[0])));
}

extern "C" void kernel_launch(void* const* d_in, const int* in_sizes, int n_in,
                              void* d_out, int out_size, void* d_ws, size_t ws_size,
                              hipStream_t stream) {
  const float* atom  = (const float*)d_in[0];
  const float* fp    = (const float*)d_in[1];
  const float* Whead = (const float*)d_in[2];
  const float* ah    = (const float*)d_in[3];
  const float* Wout  = (const float*)d_in[4];
  const float* aout  = (const float*)d_in[5];
  const float* fc1w  = (const float*)d_in[6];
  const float* fc1b  = (const float*)d_in[7];
  const float* fc2w  = (const float*)d_in[8];
  const float* fc2b  = (const float*)d_in[9];
  const float* fgw   = (const float*)d_in[10];
  const float* fgb   = (const float*)d_in[11];
  const float* ffw   = (const float*)d_in[12];
  const float* ffb   = (const float*)d_in[13];
  const float* w1    = (const float*)d_in[14];
  const float* b1    = (const float*)d_in[15];
  const float* w2    = (const float*)d_in[16];
  const float* b2    = (const float*)d_in[17];
  const int*   adj   = (const int*)d_in[18];
  float* out = (float*)d_out;

  float* ws = (float*)d_ws;
  // Aliased layout (peak ~139 MB of floats):
  float* Wh   = ws;                       // 16,777,216   [K1 w, K2 r]
  float* Wh2  = ws;                       //  9,830,400   [K3 w .. K6 r]  (Wh dead)
  float* p2   = ws + 9830400;             //  4,194,304   [K5 w, K6 r]
  float* sb   = ws + 16777216;            //    262,144
  float* db   = ws + 17039360;            //    262,144
  float* hb   = ws + 17301504;            // 16,777,216   [K2 w, K3 r]
  float* ob   = ws + 17301504;            //  9,830,400   [K6 w ..]  (hb dead)
  float* s2   = ws + 34078720;
  float* d2   = s2 + 32768;
  float* mxb  = d2 + 32768;
  float* lsb  = mxb + 32768;
  float* gat  = lsb + 32768;              //  76,800
  float* fpn1 = gat + 76800;              // 131,072
  float* fpn2 = fpn1 + 131072;            //  76,800
  float* xcat = fpn2 + 76800;             // 153,600
  float* yb   = xcat + 153600;            //  76,800

  // FPN branch (independent)
  gemm_sA<4><<<64, 512, 0, stream>>>(fp,   fc1w, fc1b, fpn1, FPD_, FP2_, FP2_, 1);
  gemm_sA<4><<<64, 320, 0, stream>>>(fpn1, fc2w, fc2b, fpn2, FP2_, HID_, HID_, 0);

  // GAT stage 1
  k1_wh<<<dim3(2048, 8), 64, 0, stream>>>(atom, Whead, ah, Wh, sb, db);
  k2_attn1<<<8192, 256, 0, stream>>>(Wh, sb, db, adj, hb);

  // Wh2 = h @ W_out  (M=32768, K=512, N=300)
  gemm_sA<16><<<2048, 320, 0, stream>>>(hb, Wout, nullptr, Wh2, 512, HID_, HID_, 0);

  // GAT stage 2
  k4_sd2<<<8192, 256, 0, stream>>>(Wh2, aout, s2, d2);
  k5_p2<<<8192, 256, 0, stream>>>(s2, d2, adj, p2);
  k6_out<<<2048, 320, 0, stream>>>(p2, Wh2, ob);
  k7_lse<<<8192, 256, 0, stream>>>(ob, mxb, lsb);
  k8_mean<<<256, 320, 0, stream>>>(ob, mxb, lsb, gat);

  // Head
  gemm_sA<4><<<64, 320, 0, stream>>>(gat,  fgw, fgb, xcat,       HID_, HID_, 2 * HID_, 1);
  gemm_sA<4><<<64, 320, 0, stream>>>(fpn2, ffw, ffb, xcat + 300, HID_, HID_, 2 * HID_, 1);
  gemm_sA<4><<<64, 320, 0, stream>>>(xcat, w1,  b1,  yb,         2 * HID_, HID_, HID_, 1);
  k_final<<<64, 256, 0, stream>>>(yb, w2, b2, out);
}

// Round 3
// 1770.733 us; speedup vs baseline: 1.2209x; 1.2209x over previous
//
#include <hip/hip_runtime.h>
#include <math.h>

// Problem constants
#define B_    256
#define N_    128
#define F_    133
#define H_    8
#define ND_   64     // NHID
#define HID_  300
#define FPD_  1489
#define FP2_  512
#define ALPHA_ 0.2f
#define NEG_  -9.0e15f

__device__ __forceinline__ float wred_sum(float v) {
#pragma unroll
  for (int m = 32; m >= 1; m >>= 1) v += __shfl_xor(v, m, 64);
  return v;
}
__device__ __forceinline__ float wred_max(float v) {
#pragma unroll
  for (int m = 32; m >= 1; m >>= 1) v = fmaxf(v, __shfl_xor(v, m, 64));
  return v;
}
__device__ __forceinline__ float lrelu(float x) { return x > 0.f ? x : ALPHA_ * x; }
__device__ __forceinline__ float eluf(float x)  { return x > 0.f ? x : expf(x) - 1.f; }
__device__ __forceinline__ float rdlane(float v, int l) {
  return __int_as_float(__builtin_amdgcn_readlane(__float_as_int(v), l));
}

// K1: Wh[b,h,n,d] = sum_f A[b,n,f] * W[h,f,d];  s/d head projections fused.
// grid (2048, 8), block 64 (1 wave, lane = d). 16 rows per block.
__global__ __launch_bounds__(64) void k1_wh(
    const float* __restrict__ A, const float* __restrict__ W,
    const float* __restrict__ ah, float* __restrict__ Wh,
    float* __restrict__ sb, float* __restrict__ db) {
  const int lane = threadIdx.x;
  const int h = blockIdx.y;
  const int m0 = blockIdx.x * 16;           // flat row b*N+n
  const float* Wg = W + (size_t)h * F_ * ND_;
  float acc[16];
#pragma unroll
  for (int r = 0; r < 16; ++r) acc[r] = 0.f;
  for (int f = 0; f < F_; ++f) {
    float wv = Wg[f * ND_ + lane];
#pragma unroll
    for (int r = 0; r < 16; ++r)
      acc[r] = fmaf(A[(size_t)(m0 + r) * F_ + f], wv, acc[r]);
  }
  float a1 = ah[h * 2 * ND_ + lane];
  float a2 = ah[h * 2 * ND_ + ND_ + lane];
  const int b = m0 >> 7, n0 = m0 & (N_ - 1);
  const size_t bh = (size_t)b * H_ + h;
#pragma unroll
  for (int r = 0; r < 16; ++r) {
    Wh[(bh * N_ + n0 + r) * ND_ + lane] = acc[r];
    float sv = wred_sum(acc[r] * a1);
    float dv = wred_sum(acc[r] * a2);
    if (lane == 0) {
      sb[bh * N_ + n0 + r] = sv;
      db[bh * N_ + n0 + r] = dv;
    }
  }
}

// K2: masked softmax over j + h = elu(attn @ Wh), written as hbuf[b,i,h*64+d].
// grid 8192, block 256 (4 waves); each wave owns 8 rows of one (b,h).
__global__ __launch_bounds__(256) void k2_attn1(
    const float* __restrict__ Wh, const float* __restrict__ sb,
    const float* __restrict__ db, const int* __restrict__ adj,
    float* __restrict__ hb) {
  const int lane = threadIdx.x & 63;
  const int w = blockIdx.x * 4 + (threadIdx.x >> 6);  // 0..32767
  const int bh = w >> 4;
  const int i0 = (w & 15) * 8;
  const int b = bh >> 3, h = bh & 7;
  const float* dbase = db + (size_t)bh * N_;
  const float dv0 = dbase[lane], dv1 = dbase[64 + lane];
  float p0[8], p1[8];
#pragma unroll
  for (int r = 0; r < 8; ++r) {
    const int i = i0 + r;
    float sv = sb[(size_t)bh * N_ + i];
    const int* arow = adj + ((size_t)b * N_ + i) * N_;
    int a0 = arow[lane], a1i = arow[64 + lane];
    float e0 = a0 > 0 ? lrelu(sv + dv0) : NEG_;
    float e1 = a1i > 0 ? lrelu(sv + dv1) : NEG_;
    float mx = wred_max(fmaxf(e0, e1));
    float x0 = expf(e0 - mx), x1 = expf(e1 - mx);
    float inv = 1.f / wred_sum(x0 + x1);
    p0[r] = x0 * inv;
    p1[r] = x1 * inv;
  }
  const float* whb = Wh + (size_t)bh * N_ * ND_ + lane;
  float acc[8];
#pragma unroll
  for (int r = 0; r < 8; ++r) acc[r] = 0.f;
  for (int j = 0; j < 64; ++j) {
    float wv = whb[(size_t)j * ND_];
#pragma unroll
    for (int r = 0; r < 8; ++r) acc[r] = fmaf(rdlane(p0[r], j), wv, acc[r]);
  }
  for (int j = 0; j < 64; ++j) {
    float wv = whb[(size_t)(64 + j) * ND_];
#pragma unroll
    for (int r = 0; r < 8; ++r) acc[r] = fmaf(rdlane(p1[r], j), wv, acc[r]);
  }
  float* hrow = hb + ((size_t)b * N_ + i0) * (H_ * ND_) + h * ND_ + lane;
#pragma unroll
  for (int r = 0; r < 8; ++r) hrow[(size_t)r * (H_ * ND_)] = eluf(acc[r]);
}

// Big-M GEMM, 16 rows/block, one column per thread.
// Accumulators are four NAMED float4s (cannot go to scratch); A is read as
// wave-uniform float4 -> s_load_dwordx4 (4x fewer scalar ops than dword).
// K compile-time, k-loop unrolled by 4. BATB: B is per-batch (128 rows of A
// share one B panel of K*N). ACT: 0 none, 2 elu.
template <int K, int ACT, bool BATB>
__global__ __launch_bounds__(320) void gemm_k(
    const float* __restrict__ A, const float* __restrict__ Bm,
    float* __restrict__ C, int N) {
  const int c = threadIdx.x;
  const int r0 = blockIdx.x * 16;
  if (c >= N) return;
  const float* Ab = A + (size_t)r0 * K;
  const float* Bp = BATB ? Bm + (size_t)(r0 >> 7) * K * N : Bm;
  float4 acc0 = {0,0,0,0}, acc1 = {0,0,0,0}, acc2 = {0,0,0,0}, acc3 = {0,0,0,0};
  for (int k = 0; k < K; k += 4) {
    const float b0 = Bp[(size_t)(k + 0) * N + c];
    const float b1 = Bp[(size_t)(k + 1) * N + c];
    const float b2 = Bp[(size_t)(k + 2) * N + c];
    const float b3 = Bp[(size_t)(k + 3) * N + c];
    float4 a;
#define ROWFMA(r, comp, accv)                                        \
    a = *reinterpret_cast<const float4*>(Ab + (size_t)(r) * K + k);  \
    accv.comp = fmaf(a.x, b0, accv.comp);                            \
    accv.comp = fmaf(a.y, b1, accv.comp);                            \
    accv.comp = fmaf(a.z, b2, accv.comp);                            \
    accv.comp = fmaf(a.w, b3, accv.comp);
    ROWFMA(0,  x, acc0) ROWFMA(1,  y, acc0) ROWFMA(2,  z, acc0) ROWFMA(3,  w, acc0)
    ROWFMA(4,  x, acc1) ROWFMA(5,  y, acc1) ROWFMA(6,  z, acc1) ROWFMA(7,  w, acc1)
    ROWFMA(8,  x, acc2) ROWFMA(9,  y, acc2) ROWFMA(10, z, acc2) ROWFMA(11, w, acc2)
    ROWFMA(12, x, acc3) ROWFMA(13, y, acc3) ROWFMA(14, z, acc3) ROWFMA(15, w, acc3)
#undef ROWFMA
  }
  float outv[16] = {acc0.x, acc0.y, acc0.z, acc0.w, acc1.x, acc1.y, acc1.z, acc1.w,
                    acc2.x, acc2.y, acc2.z, acc2.w, acc3.x, acc3.y, acc3.z, acc3.w};
#pragma unroll
  for (int r = 0; r < 16; ++r) {
    float v = outv[r];
    if (ACT == 2) v = eluf(v);
    C[(size_t)(r0 + r) * N + c] = v;
  }
}

// Generic small GEMM: C[m, c] = act(sum_k A[m,k]*B[k,c] + bias[c]).
// A accesses are wave-uniform -> scalar loads. act: 0 none, 1 relu.
template <int ROWS>
__global__ void gemm_sA(const float* __restrict__ A, const float* __restrict__ Bm,
                        const float* __restrict__ bias, float* __restrict__ C,
                        int K, int N, int ldc, int act) {
  const int c = threadIdx.x;
  const int r0 = blockIdx.x * ROWS;
  if (c >= N) return;
  float acc[ROWS];
#pragma unroll
  for (int r = 0; r < ROWS; ++r) acc[r] = bias ? bias[c] : 0.f;
  for (int k = 0; k < K; ++k) {
    float bv = Bm[(size_t)k * N + c];
#pragma unroll
    for (int r = 0; r < ROWS; ++r)
      acc[r] = fmaf(A[(size_t)(r0 + r) * K + k], bv, acc[r]);
  }
#pragma unroll
  for (int r = 0; r < ROWS; ++r) {
    float v = acc[r];
    if (act == 1) v = fmaxf(v, 0.f);
    C[(size_t)(r0 + r) * ldc + c] = v;
  }
}

// K4: s2/d2 = Wh2 @ a_out halves. One wave per row.
__global__ __launch_bounds__(256) void k4_sd2(
    const float* __restrict__ Wh2, const float* __restrict__ ao,
    float* __restrict__ s2, float* __restrict__ d2) {
  const int lane = threadIdx.x & 63;
  const int row = blockIdx.x * 4 + (threadIdx.x >> 6);
  const float* wrow = Wh2 + (size_t)row * HID_;
  float as = 0.f, ad = 0.f;
  for (int c = lane; c < HID_; c += 64) {
    float v = wrow[c];
    as = fmaf(v, ao[c], as);
    ad = fmaf(v, ao[HID_ + c], ad);
  }
  as = wred_sum(as);
  ad = wred_sum(ad);
  if (lane == 0) { s2[row] = as; d2[row] = ad; }
}

// K5: attn2 probabilities p2[b,i,j]. One wave per row i.
__global__ __launch_bounds__(256) void k5_p2(
    const float* __restrict__ s2, const float* __restrict__ d2,
    const int* __restrict__ adj, float* __restrict__ p2) {
  const int lane = threadIdx.x & 63;
  const int row = blockIdx.x * 4 + (threadIdx.x >> 6);  // b*N+i
  const int b = row >> 7;
  float sv = s2[row];
  const float* drow = d2 + (size_t)b * N_;
  const int* arow = adj + (size_t)row * N_;
  float dv0 = drow[lane], dv1 = drow[64 + lane];
  int a0 = arow[lane], a1i = arow[64 + lane];
  float e0 = a0 > 0 ? lrelu(sv + dv0) : NEG_;
  float e1 = a1i > 0 ? lrelu(sv + dv1) : NEG_;
  float mx = wred_max(fmaxf(e0, e1));
  float x0 = expf(e0 - mx), x1 = expf(e1 - mx);
  float inv = 1.f / wred_sum(x0 + x1);
  p2[(size_t)row * N_ + lane] = x0 * inv;
  p2[(size_t)row * N_ + 64 + lane] = x1 * inv;
}

// K7: per-row max and log-sum-exp over 300 cols. One wave per row.
__global__ __launch_bounds__(256) void k7_lse(
    const float* __restrict__ ob, float* __restrict__ mx, float* __restrict__ ls) {
  const int lane = threadIdx.x & 63;
  const int row = blockIdx.x * 4 + (threadIdx.x >> 6);
  const float* orow = ob + (size_t)row * HID_;
  float v[5], m = -1e30f;
#pragma unroll
  for (int q = 0; q < 5; ++q) {
    int c = lane + q * 64;
    v[q] = (c < HID_) ? orow[c] : -1e30f;
    m = fmaxf(m, v[q]);
  }
  m = wred_max(m);
  float s = 0.f;
#pragma unroll
  for (int q = 0; q < 5; ++q) {
    int c = lane + q * 64;
    if (c < HID_) s += expf(v[q] - m);
  }
  s = wred_sum(s);
  if (lane == 0) { mx[row] = m; ls[row] = logf(s); }
}

// K8: gat_out[b,c] = mean_i (ob[b,i,c] - mx - ls). grid 256, block 320.
__global__ void k8_mean(const float* __restrict__ ob, const float* __restrict__ mx,
                        const float* __restrict__ ls, float* __restrict__ gat) {
  const int c = threadIdx.x;
  const int b = blockIdx.x;
  if (c >= HID_) return;
  float acc = 0.f;
  for (int i = 0; i < N_; ++i) {
    int row = b * N_ + i;
    acc += ob[(size_t)row * HID_ + c] - mx[row] - ls[row];
  }
  gat[(size_t)b * HID_ + c] = acc * (1.f / N_);
}

// out[b] = sigmoid(y[b,:] @ ffn_w2 + b2). One wave per row.
__global__ __launch_bounds__(256) void k_final(
    const float* __restrict__ y, const float* __restrict__ w2,
    const float* __restrict__ b2, float* __restrict__ out) {
  const int lane = threadIdx.x & 63;
  const int b = blockIdx.x * 4 + (threadIdx.x >> 6);
  float acc = 0.f;
  for (int c = lane; c < HID_; c += 64)
    acc = fmaf(y[(size_t)b * HID_ + c], w2[c], acc);
  acc = wred_sum(acc);
  if (lane == 0) out[b] = 1.f / (1.f + expf(-(acc + b2[0])));
}

extern "C" void kernel_launch(void* const* d_in, const int* in_sizes, int n_in,
                              void* d_out, int out_size, void* d_ws, size_t ws_size,
                              hipStream_t stream) {
  const float* atom  = (const float*)d_in[0];
  const float* fp    = (const float*)d_in[1];
  const float* Whead = (const float*)d_in[2];
  const float* ah    = (const float*)d_in[3];
  const float* Wout  = (const float*)d_in[4];
  const float* aout  = (const float*)d_in[5];
  const float* fc1w  = (const float*)d_in[6];
  const float* fc1b  = (const float*)d_in[7];
  const float* fc2w  = (const float*)d_in[8];
  const float* fc2b  = (const float*)d_in[9];
  const float* fgw   = (const float*)d_in[10];
  const float* fgb   = (const float*)d_in[11];
  const float* ffw   = (const float*)d_in[12];
  const float* ffb   = (const float*)d_in[13];
  const float* w1    = (const float*)d_in[14];
  const float* b1    = (const float*)d_in[15];
  const float* w2    = (const float*)d_in[16];
  const float* b2    = (const float*)d_in[17];
  const int*   adj   = (const int*)d_in[18];
  float* out = (float*)d_out;

  float* ws = (float*)d_ws;
  // Aliased layout (peak ~139 MB of floats):
  float* Wh   = ws;                       // 16,777,216   [K1 w, K2 r]
  float* Wh2  = ws;                       //  9,830,400   [K3 w .. K6 r]  (Wh dead)
  float* p2   = ws + 9830400;             //  4,194,304   [K5 w, K6 r]
  float* sb   = ws + 16777216;            //    262,144
  float* db   = ws + 17039360;            //    262,144
  float* hb   = ws + 17301504;            // 16,777,216   [K2 w, K3 r]
  float* ob   = ws + 17301504;            //  9,830,400   [K6 w ..]  (hb dead)
  float* s2   = ws + 34078720;
  float* d2   = s2 + 32768;
  float* mxb  = d2 + 32768;
  float* lsb  = mxb + 32768;
  float* gat  = lsb + 32768;              //  76,800
  float* fpn1 = gat + 76800;              // 131,072
  float* fpn2 = fpn1 + 131072;            //  76,800
  float* xcat = fpn2 + 76800;             // 153,600
  float* yb   = xcat + 153600;            //  76,800

  // FPN branch (independent)
  gemm_sA<4><<<64, 512, 0, stream>>>(fp,   fc1w, fc1b, fpn1, FPD_, FP2_, FP2_, 1);
  gemm_sA<4><<<64, 320, 0, stream>>>(fpn1, fc2w, fc2b, fpn2, FP2_, HID_, HID_, 0);

  // GAT stage 1
  k1_wh<<<dim3(2048, 8), 64, 0, stream>>>(atom, Whead, ah, Wh, sb, db);
  k2_attn1<<<8192, 256, 0, stream>>>(Wh, sb, db, adj, hb);

  // Wh2 = h @ W_out  (M=32768, K=512, N=300)
  gemm_k<512, 0, false><<<2048, 320, 0, stream>>>(hb, Wout, Wh2, HID_);

  // GAT stage 2
  k4_sd2<<<8192, 256, 0, stream>>>(Wh2, aout, s2, d2);
  k5_p2<<<8192, 256, 0, stream>>>(s2, d2, adj, p2);
  // ob = elu(p2 @ Wh2)  (M=32768, K=128, N=300, B batched per 128 rows)
  gemm_k<128, 2, true><<<2048, 320, 0, stream>>>(p2, Wh2, ob, HID_);
  k7_lse<<<8192, 256, 0, stream>>>(ob, mxb, lsb);
  k8_mean<<<256, 320, 0, stream>>>(ob, mxb, lsb, gat);

  // Head
  gemm_sA<4><<<64, 320, 0, stream>>>(gat,  fgw, fgb, xcat,       HID_, HID_, 2 * HID_, 1);
  gemm_sA<4><<<64, 320, 0, stream>>>(fpn2, ffw, ffb, xcat + 300, HID_, HID_, 2 * HID_, 1);
  gemm_sA<4><<<64, 320, 0, stream>>>(xcat, w1,  b1,  yb,         2 * HID_, HID_, HID_, 1);
  k_final<<<64, 256, 0, stream>>>(yb, w2, b2, out);
}

// Round 4
// 843.180 us; speedup vs baseline: 2.5640x; 2.1001x over previous
//
#include <hip/hip_runtime.h>
#include <math.h>

// Problem constants
#define B_    256
#define N_    128
#define F_    133
#define H_    8
#define ND_   64     // NHID
#define HID_  300
#define FPD_  1489
#define FP2_  512
#define ALPHA_ 0.2f
#define NEG_  -9.0e15f

__device__ __forceinline__ float wred_sum(float v) {
#pragma unroll
  for (int m = 32; m >= 1; m >>= 1) v += __shfl_xor(v, m, 64);
  return v;
}
__device__ __forceinline__ float wred_max(float v) {
#pragma unroll
  for (int m = 32; m >= 1; m >>= 1) v = fmaxf(v, __shfl_xor(v, m, 64));
  return v;
}
__device__ __forceinline__ float lrelu(float x) { return x > 0.f ? x : ALPHA_ * x; }
__device__ __forceinline__ float eluf(float x)  { return x > 0.f ? x : expf(x) - 1.f; }
__device__ __forceinline__ float rdlane(float v, int l) {
  return __int_as_float(__builtin_amdgcn_readlane(__float_as_int(v), l));
}
// 16B load at 4B alignment (safe form; compiler batches into dwordx4/dword group)
__device__ __forceinline__ float4 ld4u(const float* p) {
  float4 v;
  __builtin_memcpy(&v, p, 16);
  return v;
}

// K1: Wh[b,h,n,d] = sum_f A[b,n,f] * W[h,f,d];  s/d head projections fused.
// grid (2048, 8), block 64 (1 wave, lane = d). 16 rows per block.
// f-loop unrolled x4 with dwordx4 uniform A loads (same fp add order).
__global__ __launch_bounds__(64) void k1_wh(
    const float* __restrict__ A, const float* __restrict__ W,
    const float* __restrict__ ah, float* __restrict__ Wh,
    float* __restrict__ sb, float* __restrict__ db) {
  const int lane = threadIdx.x;
  const int h = blockIdx.y;
  const int m0 = blockIdx.x * 16;           // flat row b*N+n
  const float* Wg = W + (size_t)h * F_ * ND_;
  float acc[16];
#pragma unroll
  for (int r = 0; r < 16; ++r) acc[r] = 0.f;
  int f = 0;
  for (; f + 3 < F_; f += 4) {
    const float wv0 = Wg[(f + 0) * ND_ + lane];
    const float wv1 = Wg[(f + 1) * ND_ + lane];
    const float wv2 = Wg[(f + 2) * ND_ + lane];
    const float wv3 = Wg[(f + 3) * ND_ + lane];
#pragma unroll
    for (int r = 0; r < 16; ++r) {
      float4 a = ld4u(A + (size_t)(m0 + r) * F_ + f);
      acc[r] = fmaf(a.x, wv0, acc[r]);
      acc[r] = fmaf(a.y, wv1, acc[r]);
      acc[r] = fmaf(a.z, wv2, acc[r]);
      acc[r] = fmaf(a.w, wv3, acc[r]);
    }
  }
  for (; f < F_; ++f) {
    const float wv = Wg[f * ND_ + lane];
#pragma unroll
    for (int r = 0; r < 16; ++r)
      acc[r] = fmaf(A[(size_t)(m0 + r) * F_ + f], wv, acc[r]);
  }
  float a1 = ah[h * 2 * ND_ + lane];
  float a2 = ah[h * 2 * ND_ + ND_ + lane];
  const int b = m0 >> 7, n0 = m0 & (N_ - 1);
  const size_t bh = (size_t)b * H_ + h;
#pragma unroll
  for (int r = 0; r < 16; ++r) {
    Wh[(bh * N_ + n0 + r) * ND_ + lane] = acc[r];
    float sv = wred_sum(acc[r] * a1);
    float dv = wred_sum(acc[r] * a2);
    if (lane == 0) {
      sb[bh * N_ + n0 + r] = sv;
      db[bh * N_ + n0 + r] = dv;
    }
  }
}

// K2: masked softmax over j + h = elu(attn @ Wh), written as hbuf[b,i,h*64+d].
// grid 8192, block 256 (4 waves); each wave owns 8 rows of one (b,h).
__global__ __launch_bounds__(256) void k2_attn1(
    const float* __restrict__ Wh, const float* __restrict__ sb,
    const float* __restrict__ db, const int* __restrict__ adj,
    float* __restrict__ hb) {
  const int lane = threadIdx.x & 63;
  const int w = blockIdx.x * 4 + (threadIdx.x >> 6);  // 0..32767
  const int bh = w >> 4;
  const int i0 = (w & 15) * 8;
  const int b = bh >> 3, h = bh & 7;
  const float* dbase = db + (size_t)bh * N_;
  const float dv0 = dbase[lane], dv1 = dbase[64 + lane];
  float p0[8], p1[8];
#pragma unroll
  for (int r = 0; r < 8; ++r) {
    const int i = i0 + r;
    float sv = sb[(size_t)bh * N_ + i];
    const int* arow = adj + ((size_t)b * N_ + i) * N_;
    int a0 = arow[lane], a1i = arow[64 + lane];
    float e0 = a0 > 0 ? lrelu(sv + dv0) : NEG_;
    float e1 = a1i > 0 ? lrelu(sv + dv1) : NEG_;
    float mx = wred_max(fmaxf(e0, e1));
    float x0 = expf(e0 - mx), x1 = expf(e1 - mx);
    float inv = 1.f / wred_sum(x0 + x1);
    p0[r] = x0 * inv;
    p1[r] = x1 * inv;
  }
  const float* whb = Wh + (size_t)bh * N_ * ND_ + lane;
  float acc[8];
#pragma unroll
  for (int r = 0; r < 8; ++r) acc[r] = 0.f;
  for (int j = 0; j < 64; ++j) {
    float wv = whb[(size_t)j * ND_];
#pragma unroll
    for (int r = 0; r < 8; ++r) acc[r] = fmaf(rdlane(p0[r], j), wv, acc[r]);
  }
  for (int j = 0; j < 64; ++j) {
    float wv = whb[(size_t)(64 + j) * ND_];
#pragma unroll
    for (int r = 0; r < 8; ++r) acc[r] = fmaf(rdlane(p1[r], j), wv, acc[r]);
  }
  float* hrow = hb + ((size_t)b * N_ + i0) * (H_ * ND_) + h * ND_ + lane;
#pragma unroll
  for (int r = 0; r < 8; ++r) hrow[(size_t)r * (H_ * ND_)] = eluf(acc[r]);
}

// Big-M GEMM, 16 rows/block, one column per thread. K compile-time (mult of 4,
// rows 16B-aligned). Named float4 accumulators; uniform float4 A loads.
template <int K, int ACT, bool BATB>
__global__ __launch_bounds__(320) void gemm_k(
    const float* __restrict__ A, const float* __restrict__ Bm,
    float* __restrict__ C, int N) {
  const int c = threadIdx.x;
  const int r0 = blockIdx.x * 16;
  if (c >= N) return;
  const float* Ab = A + (size_t)r0 * K;
  const float* Bp = BATB ? Bm + (size_t)(r0 >> 7) * K * N : Bm;
  float4 acc0 = {0,0,0,0}, acc1 = {0,0,0,0}, acc2 = {0,0,0,0}, acc3 = {0,0,0,0};
  for (int k = 0; k < K; k += 4) {
    const float b0 = Bp[(size_t)(k + 0) * N + c];
    const float b1 = Bp[(size_t)(k + 1) * N + c];
    const float b2 = Bp[(size_t)(k + 2) * N + c];
    const float b3 = Bp[(size_t)(k + 3) * N + c];
    float4 a;
#define ROWFMA(r, comp, accv)                                        \
    a = *reinterpret_cast<const float4*>(Ab + (size_t)(r) * K + k);  \
    accv.comp = fmaf(a.x, b0, accv.comp);                            \
    accv.comp = fmaf(a.y, b1, accv.comp);                            \
    accv.comp = fmaf(a.z, b2, accv.comp);                            \
    accv.comp = fmaf(a.w, b3, accv.comp);
    ROWFMA(0,  x, acc0) ROWFMA(1,  y, acc0) ROWFMA(2,  z, acc0) ROWFMA(3,  w, acc0)
    ROWFMA(4,  x, acc1) ROWFMA(5,  y, acc1) ROWFMA(6,  z, acc1) ROWFMA(7,  w, acc1)
    ROWFMA(8,  x, acc2) ROWFMA(9,  y, acc2) ROWFMA(10, z, acc2) ROWFMA(11, w, acc2)
    ROWFMA(12, x, acc3) ROWFMA(13, y, acc3) ROWFMA(14, z, acc3) ROWFMA(15, w, acc3)
#undef ROWFMA
  }
  float outv[16] = {acc0.x, acc0.y, acc0.z, acc0.w, acc1.x, acc1.y, acc1.z, acc1.w,
                    acc2.x, acc2.y, acc2.z, acc2.w, acc3.x, acc3.y, acc3.z, acc3.w};
#pragma unroll
  for (int r = 0; r < 16; ++r) {
    float v = outv[r];
    if (ACT == 2) v = eluf(v);
    C[(size_t)(r0 + r) * N + c] = v;
  }
}

// Split-K partial GEMM for small-M matmuls: grid (M/ROWS, KSPLIT).
// Each block accumulates its K-chunk; partials P[ks][M][N]. No bias/act here.
template <int ROWS, int KSPLIT>
__global__ void gemm_skp(const float* __restrict__ A, const float* __restrict__ Bm,
                         float* __restrict__ P, int M, int K, int N) {
  const int c = threadIdx.x;
  const int r0 = blockIdx.x * ROWS;
  const int ks = blockIdx.y;
  if (c >= N) return;
  const int kchunk = (K + KSPLIT - 1) / KSPLIT;
  const int k0 = ks * kchunk;
  const int k1 = (k0 + kchunk < K) ? (k0 + kchunk) : K;
  float acc[ROWS];
#pragma unroll
  for (int r = 0; r < ROWS; ++r) acc[r] = 0.f;
  int k = k0;
  for (; k + 3 < k1; k += 4) {
    const float b0 = Bm[(size_t)(k + 0) * N + c];
    const float b1 = Bm[(size_t)(k + 1) * N + c];
    const float b2 = Bm[(size_t)(k + 2) * N + c];
    const float b3 = Bm[(size_t)(k + 3) * N + c];
#pragma unroll
    for (int r = 0; r < ROWS; ++r) {
      float4 a = ld4u(A + (size_t)(r0 + r) * K + k);
      acc[r] = fmaf(a.x, b0, acc[r]);
      acc[r] = fmaf(a.y, b1, acc[r]);
      acc[r] = fmaf(a.z, b2, acc[r]);
      acc[r] = fmaf(a.w, b3, acc[r]);
    }
  }
  for (; k < k1; ++k) {
    const float bv = Bm[(size_t)k * N + c];
#pragma unroll
    for (int r = 0; r < ROWS; ++r)
      acc[r] = fmaf(A[(size_t)(r0 + r) * K + k], bv, acc[r]);
  }
#pragma unroll
  for (int r = 0; r < ROWS; ++r)
    P[((size_t)ks * M + r0 + r) * N + c] = acc[r];
}

// Reduce split-K partials + bias + act. act: 0 none, 1 relu.
template <int KSPLIT>
__global__ void k_red(const float* __restrict__ P, const float* __restrict__ bias,
                      float* __restrict__ C, int M, int N, int ldc, int act) {
  const int idx = blockIdx.x * 256 + threadIdx.x;
  if (idx >= M * N) return;
  const int m = idx / N, c = idx - m * N;
  float v = 0.f;
#pragma unroll
  for (int p = 0; p < KSPLIT; ++p) v += P[(size_t)p * M * N + idx];
  if (bias) v += bias[c];
  if (act == 1) v = fmaxf(v, 0.f);
  C[(size_t)m * ldc + c] = v;
}

// K4: s2/d2 = Wh2 @ a_out halves. One wave per row.
__global__ __launch_bounds__(256) void k4_sd2(
    const float* __restrict__ Wh2, const float* __restrict__ ao,
    float* __restrict__ s2, float* __restrict__ d2) {
  const int lane = threadIdx.x & 63;
  const int row = blockIdx.x * 4 + (threadIdx.x >> 6);
  const float* wrow = Wh2 + (size_t)row * HID_;
  float as = 0.f, ad = 0.f;
  for (int c = lane; c < HID_; c += 64) {
    float v = wrow[c];
    as = fmaf(v, ao[c], as);
    ad = fmaf(v, ao[HID_ + c], ad);
  }
  as = wred_sum(as);
  ad = wred_sum(ad);
  if (lane == 0) { s2[row] = as; d2[row] = ad; }
}

// K5: attn2 probabilities p2[b,i,j]. One wave per row i.
__global__ __launch_bounds__(256) void k5_p2(
    const float* __restrict__ s2, const float* __restrict__ d2,
    const int* __restrict__ adj, float* __restrict__ p2) {
  const int lane = threadIdx.x & 63;
  const int row = blockIdx.x * 4 + (threadIdx.x >> 6);  // b*N+i
  const int b = row >> 7;
  float sv = s2[row];
  const float* drow = d2 + (size_t)b * N_;
  const int* arow = adj + (size_t)row * N_;
  float dv0 = drow[lane], dv1 = drow[64 + lane];
  int a0 = arow[lane], a1i = arow[64 + lane];
  float e0 = a0 > 0 ? lrelu(sv + dv0) : NEG_;
  float e1 = a1i > 0 ? lrelu(sv + dv1) : NEG_;
  float mx = wred_max(fmaxf(e0, e1));
  float x0 = expf(e0 - mx), x1 = expf(e1 - mx);
  float inv = 1.f / wred_sum(x0 + x1);
  p2[(size_t)row * N_ + lane] = x0 * inv;
  p2[(size_t)row * N_ + 64 + lane] = x1 * inv;
}

// K7: per-row max and log-sum-exp over 300 cols. One wave per row.
__global__ __launch_bounds__(256) void k7_lse(
    const float* __restrict__ ob, float* __restrict__ mx, float* __restrict__ ls) {
  const int lane = threadIdx.x & 63;
  const int row = blockIdx.x * 4 + (threadIdx.x >> 6);
  const float* orow = ob + (size_t)row * HID_;
  float v[5], m = -1e30f;
#pragma unroll
  for (int q = 0; q < 5; ++q) {
    int c = lane + q * 64;
    v[q] = (c < HID_) ? orow[c] : -1e30f;
    m = fmaxf(m, v[q]);
  }
  m = wred_max(m);
  float s = 0.f;
#pragma unroll
  for (int q = 0; q < 5; ++q) {
    int c = lane + q * 64;
    if (c < HID_) s += expf(v[q] - m);
  }
  s = wred_sum(s);
  if (lane == 0) { mx[row] = m; ls[row] = logf(s); }
}

// K8: gat_out[b,c] = mean_i (ob[b,i,c] - mx - ls). grid 256, block 320.
__global__ void k8_mean(const float* __restrict__ ob, const float* __restrict__ mx,
                        const float* __restrict__ ls, float* __restrict__ gat) {
  const int c = threadIdx.x;
  const int b = blockIdx.x;
  if (c >= HID_) return;
  float acc = 0.f;
  for (int i = 0; i < N_; ++i) {
    int row = b * N_ + i;
    acc += ob[(size_t)row * HID_ + c] - mx[row] - ls[row];
  }
  gat[(size_t)b * HID_ + c] = acc * (1.f / N_);
}

// out[b] = sigmoid(y[b,:] @ ffn_w2 + b2). One wave per row.
__global__ __launch_bounds__(256) void k_final(
    const float* __restrict__ y, const float* __restrict__ w2,
    const float* __restrict__ b2, float* __restrict__ out) {
  const int lane = threadIdx.x & 63;
  const int b = blockIdx.x * 4 + (threadIdx.x >> 6);
  float acc = 0.f;
  for (int c = lane; c < HID_; c += 64)
    acc = fmaf(y[(size_t)b * HID_ + c], w2[c], acc);
  acc = wred_sum(acc);
  if (lane == 0) out[b] = 1.f / (1.f + expf(-(acc + b2[0])));
}

extern "C" void kernel_launch(void* const* d_in, const int* in_sizes, int n_in,
                              void* d_out, int out_size, void* d_ws, size_t ws_size,
                              hipStream_t stream) {
  const float* atom  = (const float*)d_in[0];
  const float* fp    = (const float*)d_in[1];
  const float* Whead = (const float*)d_in[2];
  const float* ah    = (const float*)d_in[3];
  const float* Wout  = (const float*)d_in[4];
  const float* aout  = (const float*)d_in[5];
  const float* fc1w  = (const float*)d_in[6];
  const float* fc1b  = (const float*)d_in[7];
  const float* fc2w  = (const float*)d_in[8];
  const float* fc2b  = (const float*)d_in[9];
  const float* fgw   = (const float*)d_in[10];
  const float* fgb   = (const float*)d_in[11];
  const float* ffw   = (const float*)d_in[12];
  const float* ffb   = (const float*)d_in[13];
  const float* w1    = (const float*)d_in[14];
  const float* b1    = (const float*)d_in[15];
  const float* w2    = (const float*)d_in[16];
  const float* b2    = (const float*)d_in[17];
  const int*   adj   = (const int*)d_in[18];
  float* out = (float*)d_out;

  float* ws = (float*)d_ws;
  // Aliased layout (peak ~139 MB of floats):
  float* Wh   = ws;                       // 16,777,216   [K1 w, K2 r]
  float* Wh2  = ws;                       //  9,830,400   [K3 w .. K6 r]  (Wh dead)
  float* pbuf = ws;                       // <=1,048,576  [split-K partials; only
                                          //  live before k1 and after k8]
  float* p2   = ws + 9830400;             //  4,194,304   [K5 w, K6 r]
  float* sb   = ws + 16777216;            //    262,144
  float* db   = ws + 17039360;            //    262,144
  float* hb   = ws + 17301504;            // 16,777,216   [K2 w, K3 r]
  float* ob   = ws + 17301504;            //  9,830,400   [K6 w ..]  (hb dead)
  float* s2   = ws + 34078720;
  float* d2   = s2 + 32768;
  float* mxb  = d2 + 32768;
  float* lsb  = mxb + 32768;
  float* gat  = lsb + 32768;              //  76,800
  float* fpn1 = gat + 76800;              // 131,072
  float* fpn2 = fpn1 + 131072;            //  76,800
  float* xcat = fpn2 + 76800;             // 153,600
  float* yb   = xcat + 153600;            //  76,800

  // FPN branch (before k1 so pbuf aliasing of Wh region is safe)
  gemm_skp<4, 8><<<dim3(64, 8), 512, 0, stream>>>(fp, fc1w, pbuf, B_, FPD_, FP2_);
  k_red<8><<<512, 256, 0, stream>>>(pbuf, fc1b, fpn1, B_, FP2_, FP2_, 1);
  gemm_skp<4, 4><<<dim3(64, 4), 320, 0, stream>>>(fpn1, fc2w, pbuf, B_, FP2_, HID_);
  k_red<4><<<300, 256, 0, stream>>>(pbuf, fc2b, fpn2, B_, HID_, HID_, 0);

  // GAT stage 1
  k1_wh<<<dim3(2048, 8), 64, 0, stream>>>(atom, Whead, ah, Wh, sb, db);
  k2_attn1<<<8192, 256, 0, stream>>>(Wh, sb, db, adj, hb);

  // Wh2 = h @ W_out  (M=32768, K=512, N=300)
  gemm_k<512, 0, false><<<2048, 320, 0, stream>>>(hb, Wout, Wh2, HID_);

  // GAT stage 2
  k4_sd2<<<8192, 256, 0, stream>>>(Wh2, aout, s2, d2);
  k5_p2<<<8192, 256, 0, stream>>>(s2, d2, adj, p2);
  // ob = elu(p2 @ Wh2)  (M=32768, K=128, N=300, B batched per 128 rows)
  gemm_k<128, 2, true><<<2048, 320, 0, stream>>>(p2, Wh2, ob, HID_);
  k7_lse<<<8192, 256, 0, stream>>>(ob, mxb, lsb);
  k8_mean<<<256, 320, 0, stream>>>(ob, mxb, lsb, gat);

  // Head (after k8: entire low ws region dead -> pbuf reuse is safe)
  gemm_skp<4, 4><<<dim3(64, 4), 320, 0, stream>>>(gat, fgw, pbuf, B_, HID_, HID_);
  k_red<4><<<300, 256, 0, stream>>>(pbuf, fgb, xcat, B_, HID_, 2 * HID_, 1);
  gemm_skp<4, 4><<<dim3(64, 4), 320, 0, stream>>>(fpn2, ffw, pbuf, B_, HID_, HID_);
  k_red<4><<<300, 256, 0, stream>>>(pbuf, ffb, xcat + 300, B_, HID_, 2 * HID_, 1);
  gemm_skp<4, 4><<<dim3(64, 4), 320, 0, stream>>>(xcat, w1, pbuf, B_, 2 * HID_, HID_);
  k_red<4><<<300, 256, 0, stream>>>(pbuf, b1, yb, B_, HID_, HID_, 1);
  k_final<<<64, 256, 0, stream>>>(yb, w2, b2, out);
}

// Round 5
// 724.556 us; speedup vs baseline: 2.9838x; 1.1637x over previous
//
#include <hip/hip_runtime.h>
#include <math.h>

// Problem constants
#define B_    256
#define N_    128
#define F_    133
#define H_    8
#define ND_   64     // NHID
#define HID_  300
#define FPD_  1489
#define FP2_  512
#define ALPHA_ 0.2f
#define NEG_  -9.0e15f

__device__ __forceinline__ float wred_sum(float v) {
#pragma unroll
  for (int m = 32; m >= 1; m >>= 1) v += __shfl_xor(v, m, 64);
  return v;
}
__device__ __forceinline__ float wred_max(float v) {
#pragma unroll
  for (int m = 32; m >= 1; m >>= 1) v = fmaxf(v, __shfl_xor(v, m, 64));
  return v;
}
__device__ __forceinline__ float lrelu(float x) { return x > 0.f ? x : ALPHA_ * x; }
__device__ __forceinline__ float eluf(float x)  { return x > 0.f ? x : expf(x) - 1.f; }
__device__ __forceinline__ float rdlane(float v, int l) {
  return __int_as_float(__builtin_amdgcn_readlane(__float_as_int(v), l));
}
// 16B load at 4B alignment (safe form)
__device__ __forceinline__ float4 ld4u(const float* p) {
  float4 v;
  __builtin_memcpy(&v, p, 16);
  return v;
}

// K1: Wh[b,h,n,d] = sum_f A[b,n,f] * W[h,f,d];  s/d projections fused.
// grid 2048, block 512 (8 waves; wave w = head h, lane = d). 16 rows/block.
// A tile staged in LDS once, shared by all 8 heads (was 8x scalar-streamed).
__global__ __launch_bounds__(512) void k1_wh(
    const float* __restrict__ A, const float* __restrict__ W,
    const float* __restrict__ ah, float* __restrict__ Wh,
    float* __restrict__ sb, float* __restrict__ db) {
  __shared__ __align__(16) float As[16 * 136];  // ld=136 -> 16B-aligned chunks
  const int tid = threadIdx.x;
  const int lane = tid & 63;
  const int h = tid >> 6;
  const int m0 = blockIdx.x * 16;           // flat row b*N+n
  {
    const int r = tid >> 5;                 // 16 rows x 32 threads
    const int f0 = tid & 31;
    for (int f = f0; f < F_; f += 32)
      As[r * 136 + f] = A[(size_t)(m0 + r) * F_ + f];
  }
  __syncthreads();
  const float* Wg = W + (size_t)h * F_ * ND_;
  float acc[16];
#pragma unroll
  for (int r = 0; r < 16; ++r) acc[r] = 0.f;
  int f = 0;
  for (; f + 3 < F_; f += 4) {
    const float wv0 = Wg[(f + 0) * ND_ + lane];
    const float wv1 = Wg[(f + 1) * ND_ + lane];
    const float wv2 = Wg[(f + 2) * ND_ + lane];
    const float wv3 = Wg[(f + 3) * ND_ + lane];
#pragma unroll
    for (int r = 0; r < 16; ++r) {
      float4 a = *reinterpret_cast<const float4*>(&As[r * 136 + f]);
      acc[r] = fmaf(a.x, wv0, acc[r]);
      acc[r] = fmaf(a.y, wv1, acc[r]);
      acc[r] = fmaf(a.z, wv2, acc[r]);
      acc[r] = fmaf(a.w, wv3, acc[r]);
    }
  }
  for (; f < F_; ++f) {
    const float wv = Wg[f * ND_ + lane];
#pragma unroll
    for (int r = 0; r < 16; ++r)
      acc[r] = fmaf(As[r * 136 + f], wv, acc[r]);
  }
  float a1 = ah[h * 2 * ND_ + lane];
  float a2 = ah[h * 2 * ND_ + ND_ + lane];
  const int b = m0 >> 7, n0 = m0 & (N_ - 1);
  const size_t bh = (size_t)b * H_ + h;
#pragma unroll
  for (int r = 0; r < 16; ++r) {
    Wh[(bh * N_ + n0 + r) * ND_ + lane] = acc[r];
    float sv = wred_sum(acc[r] * a1);
    float dv = wred_sum(acc[r] * a2);
    if (lane == 0) {
      sb[bh * N_ + n0 + r] = sv;
      db[bh * N_ + n0 + r] = dv;
    }
  }
}

// K2: masked softmax over j + h = elu(attn @ Wh), written as hbuf[b,i,h*64+d].
// grid 8192, block 256 (4 waves); each wave owns 8 rows of one (b,h).
__global__ __launch_bounds__(256) void k2_attn1(
    const float* __restrict__ Wh, const float* __restrict__ sb,
    const float* __restrict__ db, const int* __restrict__ adj,
    float* __restrict__ hb) {
  const int lane = threadIdx.x & 63;
  const int w = blockIdx.x * 4 + (threadIdx.x >> 6);  // 0..32767
  const int bh = w >> 4;
  const int i0 = (w & 15) * 8;
  const int b = bh >> 3, h = bh & 7;
  const float* dbase = db + (size_t)bh * N_;
  const float dv0 = dbase[lane], dv1 = dbase[64 + lane];
  float p0[8], p1[8];
#pragma unroll
  for (int r = 0; r < 8; ++r) {
    const int i = i0 + r;
    float sv = sb[(size_t)bh * N_ + i];
    const int* arow = adj + ((size_t)b * N_ + i) * N_;
    int a0 = arow[lane], a1i = arow[64 + lane];
    float e0 = a0 > 0 ? lrelu(sv + dv0) : NEG_;
    float e1 = a1i > 0 ? lrelu(sv + dv1) : NEG_;
    float mx = wred_max(fmaxf(e0, e1));
    float x0 = expf(e0 - mx), x1 = expf(e1 - mx);
    float inv = 1.f / wred_sum(x0 + x1);
    p0[r] = x0 * inv;
    p1[r] = x1 * inv;
  }
  const float* whb = Wh + (size_t)bh * N_ * ND_ + lane;
  float acc[8];
#pragma unroll
  for (int r = 0; r < 8; ++r) acc[r] = 0.f;
  for (int j = 0; j < 64; ++j) {
    float wv = whb[(size_t)j * ND_];
#pragma unroll
    for (int r = 0; r < 8; ++r) acc[r] = fmaf(rdlane(p0[r], j), wv, acc[r]);
  }
  for (int j = 0; j < 64; ++j) {
    float wv = whb[(size_t)(64 + j) * ND_];
#pragma unroll
    for (int r = 0; r < 8; ++r) acc[r] = fmaf(rdlane(p1[r], j), wv, acc[r]);
  }
  float* hrow = hb + ((size_t)b * N_ + i0) * (H_ * ND_) + h * ND_ + lane;
#pragma unroll
  for (int r = 0; r < 8; ++r) hrow[(size_t)r * (H_ * ND_)] = eluf(acc[r]);
}

// Big-M GEMM, 16 rows/block, one column per thread. A tile (16xK) staged in
// LDS via coalesced vector loads; k-loop reads it as uniform ds_read_b128
// (broadcast). B register-prefetched one chunk ahead. FMA order identical
// to previous rounds (bitwise-stable output).
template <int K, int ACT, bool BATB>
__global__ __launch_bounds__(320) void gemm_k(
    const float* __restrict__ A, const float* __restrict__ Bm,
    float* __restrict__ C, int N) {
  __shared__ __align__(16) float As[16 * K];
  const int c = threadIdx.x;
  const int r0 = blockIdx.x * 16;
  const float* Ab = A + (size_t)r0 * K;
  for (int idx = threadIdx.x * 4; idx < 16 * K; idx += 320 * 4) {
    *reinterpret_cast<float4*>(&As[idx]) =
        *reinterpret_cast<const float4*>(Ab + idx);
  }
  __syncthreads();
  if (c >= N) return;
  const float* Bp = BATB ? Bm + (size_t)(r0 >> 7) * K * N : Bm;
  float4 acc0 = {0,0,0,0}, acc1 = {0,0,0,0}, acc2 = {0,0,0,0}, acc3 = {0,0,0,0};
  float b0n = Bp[c], b1n = Bp[(size_t)N + c],
        b2n = Bp[(size_t)2 * N + c], b3n = Bp[(size_t)3 * N + c];
  for (int k = 0; k < K; k += 4) {
    const float b0 = b0n, b1 = b1n, b2 = b2n, b3 = b3n;
    if (k + 4 < K) {
      b0n = Bp[(size_t)(k + 4) * N + c];
      b1n = Bp[(size_t)(k + 5) * N + c];
      b2n = Bp[(size_t)(k + 6) * N + c];
      b3n = Bp[(size_t)(k + 7) * N + c];
    }
    float4 a;
#define ROWFMA(r, comp, accv)                                  \
    a = *reinterpret_cast<const float4*>(&As[(r) * K + k]);    \
    accv.comp = fmaf(a.x, b0, accv.comp);                      \
    accv.comp = fmaf(a.y, b1, accv.comp);                      \
    accv.comp = fmaf(a.z, b2, accv.comp);                      \
    accv.comp = fmaf(a.w, b3, accv.comp);
    ROWFMA(0,  x, acc0) ROWFMA(1,  y, acc0) ROWFMA(2,  z, acc0) ROWFMA(3,  w, acc0)
    ROWFMA(4,  x, acc1) ROWFMA(5,  y, acc1) ROWFMA(6,  z, acc1) ROWFMA(7,  w, acc1)
    ROWFMA(8,  x, acc2) ROWFMA(9,  y, acc2) ROWFMA(10, z, acc2) ROWFMA(11, w, acc2)
    ROWFMA(12, x, acc3) ROWFMA(13, y, acc3) ROWFMA(14, z, acc3) ROWFMA(15, w, acc3)
#undef ROWFMA
  }
  float outv[16] = {acc0.x, acc0.y, acc0.z, acc0.w, acc1.x, acc1.y, acc1.z, acc1.w,
                    acc2.x, acc2.y, acc2.z, acc2.w, acc3.x, acc3.y, acc3.z, acc3.w};
#pragma unroll
  for (int r = 0; r < 16; ++r) {
    float v = outv[r];
    if (ACT == 2) v = eluf(v);
    C[(size_t)(r0 + r) * N + c] = v;
  }
}

// Split-K partial GEMM for small-M matmuls: grid (M/ROWS, KSPLIT).
template <int ROWS, int KSPLIT>
__global__ void gemm_skp(const float* __restrict__ A, const float* __restrict__ Bm,
                         float* __restrict__ P, int M, int K, int N) {
  const int c = threadIdx.x;
  const int r0 = blockIdx.x * ROWS;
  const int ks = blockIdx.y;
  if (c >= N) return;
  const int kchunk = (K + KSPLIT - 1) / KSPLIT;
  const int k0 = ks * kchunk;
  const int k1 = (k0 + kchunk < K) ? (k0 + kchunk) : K;
  float acc[ROWS];
#pragma unroll
  for (int r = 0; r < ROWS; ++r) acc[r] = 0.f;
  int k = k0;
  for (; k + 3 < k1; k += 4) {
    const float b0 = Bm[(size_t)(k + 0) * N + c];
    const float b1 = Bm[(size_t)(k + 1) * N + c];
    const float b2 = Bm[(size_t)(k + 2) * N + c];
    const float b3 = Bm[(size_t)(k + 3) * N + c];
#pragma unroll
    for (int r = 0; r < ROWS; ++r) {
      float4 a = ld4u(A + (size_t)(r0 + r) * K + k);
      acc[r] = fmaf(a.x, b0, acc[r]);
      acc[r] = fmaf(a.y, b1, acc[r]);
      acc[r] = fmaf(a.z, b2, acc[r]);
      acc[r] = fmaf(a.w, b3, acc[r]);
    }
  }
  for (; k < k1; ++k) {
    const float bv = Bm[(size_t)k * N + c];
#pragma unroll
    for (int r = 0; r < ROWS; ++r)
      acc[r] = fmaf(A[(size_t)(r0 + r) * K + k], bv, acc[r]);
  }
#pragma unroll
  for (int r = 0; r < ROWS; ++r)
    P[((size_t)ks * M + r0 + r) * N + c] = acc[r];
}

// Reduce split-K partials + bias + act. act: 0 none, 1 relu.
template <int KSPLIT>
__global__ void k_red(const float* __restrict__ P, const float* __restrict__ bias,
                      float* __restrict__ C, int M, int N, int ldc, int act) {
  const int idx = blockIdx.x * 256 + threadIdx.x;
  if (idx >= M * N) return;
  const int m = idx / N, c = idx - m * N;
  float v = 0.f;
#pragma unroll
  for (int p = 0; p < KSPLIT; ++p) v += P[(size_t)p * M * N + idx];
  if (bias) v += bias[c];
  if (act == 1) v = fmaxf(v, 0.f);
  C[(size_t)m * ldc + c] = v;
}

// K4: s2/d2 = Wh2 @ a_out halves. One wave per row.
__global__ __launch_bounds__(256) void k4_sd2(
    const float* __restrict__ Wh2, const float* __restrict__ ao,
    float* __restrict__ s2, float* __restrict__ d2) {
  const int lane = threadIdx.x & 63;
  const int row = blockIdx.x * 4 + (threadIdx.x >> 6);
  const float* wrow = Wh2 + (size_t)row * HID_;
  float as = 0.f, ad = 0.f;
  for (int c = lane; c < HID_; c += 64) {
    float v = wrow[c];
    as = fmaf(v, ao[c], as);
    ad = fmaf(v, ao[HID_ + c], ad);
  }
  as = wred_sum(as);
  ad = wred_sum(ad);
  if (lane == 0) { s2[row] = as; d2[row] = ad; }
}

// K5: attn2 probabilities p2[b,i,j]. One wave per row i.
__global__ __launch_bounds__(256) void k5_p2(
    const float* __restrict__ s2, const float* __restrict__ d2,
    const int* __restrict__ adj, float* __restrict__ p2) {
  const int lane = threadIdx.x & 63;
  const int row = blockIdx.x * 4 + (threadIdx.x >> 6);  // b*N+i
  const int b = row >> 7;
  float sv = s2[row];
  const float* drow = d2 + (size_t)b * N_;
  const int* arow = adj + (size_t)row * N_;
  float dv0 = drow[lane], dv1 = drow[64 + lane];
  int a0 = arow[lane], a1i = arow[64 + lane];
  float e0 = a0 > 0 ? lrelu(sv + dv0) : NEG_;
  float e1 = a1i > 0 ? lrelu(sv + dv1) : NEG_;
  float mx = wred_max(fmaxf(e0, e1));
  float x0 = expf(e0 - mx), x1 = expf(e1 - mx);
  float inv = 1.f / wred_sum(x0 + x1);
  p2[(size_t)row * N_ + lane] = x0 * inv;
  p2[(size_t)row * N_ + 64 + lane] = x1 * inv;
}

// K7: per-row max and log-sum-exp over 300 cols. One wave per row.
__global__ __launch_bounds__(256) void k7_lse(
    const float* __restrict__ ob, float* __restrict__ mx, float* __restrict__ ls) {
  const int lane = threadIdx.x & 63;
  const int row = blockIdx.x * 4 + (threadIdx.x >> 6);
  const float* orow = ob + (size_t)row * HID_;
  float v[5], m = -1e30f;
#pragma unroll
  for (int q = 0; q < 5; ++q) {
    int c = lane + q * 64;
    v[q] = (c < HID_) ? orow[c] : -1e30f;
    m = fmaxf(m, v[q]);
  }
  m = wred_max(m);
  float s = 0.f;
#pragma unroll
  for (int q = 0; q < 5; ++q) {
    int c = lane + q * 64;
    if (c < HID_) s += expf(v[q] - m);
  }
  s = wred_sum(s);
  if (lane == 0) { mx[row] = m; ls[row] = logf(s); }
}

// K8: gat_out[b,c] = mean_i (ob[b,i,c] - mx - ls). grid 256, block 320.
__global__ void k8_mean(const float* __restrict__ ob, const float* __restrict__ mx,
                        const float* __restrict__ ls, float* __restrict__ gat) {
  const int c = threadIdx.x;
  const int b = blockIdx.x;
  if (c >= HID_) return;
  float acc = 0.f;
  for (int i = 0; i < N_; ++i) {
    int row = b * N_ + i;
    acc += ob[(size_t)row * HID_ + c] - mx[row] - ls[row];
  }
  gat[(size_t)b * HID_ + c] = acc * (1.f / N_);
}

// out[b] = sigmoid(y[b,:] @ ffn_w2 + b2). One wave per row.
__global__ __launch_bounds__(256) void k_final(
    const float* __restrict__ y, const float* __restrict__ w2,
    const float* __restrict__ b2, float* __restrict__ out) {
  const int lane = threadIdx.x & 63;
  const int b = blockIdx.x * 4 + (threadIdx.x >> 6);
  float acc = 0.f;
  for (int c = lane; c < HID_; c += 64)
    acc = fmaf(y[(size_t)b * HID_ + c], w2[c], acc);
  acc = wred_sum(acc);
  if (lane == 0) out[b] = 1.f / (1.f + expf(-(acc + b2[0])));
}

extern "C" void kernel_launch(void* const* d_in, const int* in_sizes, int n_in,
                              void* d_out, int out_size, void* d_ws, size_t ws_size,
                              hipStream_t stream) {
  const float* atom  = (const float*)d_in[0];
  const float* fp    = (const float*)d_in[1];
  const float* Whead = (const float*)d_in[2];
  const float* ah    = (const float*)d_in[3];
  const float* Wout  = (const float*)d_in[4];
  const float* aout  = (const float*)d_in[5];
  const float* fc1w  = (const float*)d_in[6];
  const float* fc1b  = (const float*)d_in[7];
  const float* fc2w  = (const float*)d_in[8];
  const float* fc2b  = (const float*)d_in[9];
  const float* fgw   = (const float*)d_in[10];
  const float* fgb   = (const float*)d_in[11];
  const float* ffw   = (const float*)d_in[12];
  const float* ffb   = (const float*)d_in[13];
  const float* w1    = (const float*)d_in[14];
  const float* b1    = (const float*)d_in[15];
  const float* w2    = (const float*)d_in[16];
  const float* b2    = (const float*)d_in[17];
  const int*   adj   = (const int*)d_in[18];
  float* out = (float*)d_out;

  float* ws = (float*)d_ws;
  // Aliased layout (peak ~139 MB of floats):
  float* Wh   = ws;                       // 16,777,216   [K1 w, K2 r]
  float* Wh2  = ws;                       //  9,830,400   [K3 w .. K6 r]  (Wh dead)
  float* pbuf = ws;                       // <=1,048,576  [split-K partials; only
                                          //  live before k1 and after k8]
  float* p2   = ws + 9830400;             //  4,194,304   [K5 w, K6 r]
  float* sb   = ws + 16777216;            //    262,144
  float* db   = ws + 17039360;            //    262,144
  float* hb   = ws + 17301504;            // 16,777,216   [K2 w, K3 r]
  float* ob   = ws + 17301504;            //  9,830,400   [K6 w ..]  (hb dead)
  float* s2   = ws + 34078720;
  float* d2   = s2 + 32768;
  float* mxb  = d2 + 32768;
  float* lsb  = mxb + 32768;
  float* gat  = lsb + 32768;              //  76,800
  float* fpn1 = gat + 76800;              // 131,072
  float* fpn2 = fpn1 + 131072;            //  76,800
  float* xcat = fpn2 + 76800;             // 153,600
  float* yb   = xcat + 153600;            //  76,800

  // FPN branch (before k1 so pbuf aliasing of Wh region is safe)
  gemm_skp<4, 8><<<dim3(64, 8), 512, 0, stream>>>(fp, fc1w, pbuf, B_, FPD_, FP2_);
  k_red<8><<<512, 256, 0, stream>>>(pbuf, fc1b, fpn1, B_, FP2_, FP2_, 1);
  gemm_skp<4, 4><<<dim3(64, 4), 320, 0, stream>>>(fpn1, fc2w, pbuf, B_, FP2_, HID_);
  k_red<4><<<300, 256, 0, stream>>>(pbuf, fc2b, fpn2, B_, HID_, HID_, 0);

  // GAT stage 1
  k1_wh<<<2048, 512, 0, stream>>>(atom, Whead, ah, Wh, sb, db);
  k2_attn1<<<8192, 256, 0, stream>>>(Wh, sb, db, adj, hb);

  // Wh2 = h @ W_out  (M=32768, K=512, N=300)
  gemm_k<512, 0, false><<<2048, 320, 0, stream>>>(hb, Wout, Wh2, HID_);

  // GAT stage 2
  k4_sd2<<<8192, 256, 0, stream>>>(Wh2, aout, s2, d2);
  k5_p2<<<8192, 256, 0, stream>>>(s2, d2, adj, p2);
  // ob = elu(p2 @ Wh2)  (M=32768, K=128, N=300, B batched per 128 rows)
  gemm_k<128, 2, true><<<2048, 320, 0, stream>>>(p2, Wh2, ob, HID_);
  k7_lse<<<8192, 256, 0, stream>>>(ob, mxb, lsb);
  k8_mean<<<256, 320, 0, stream>>>(ob, mxb, lsb, gat);

  // Head (after k8: entire low ws region dead -> pbuf reuse is safe)
  gemm_skp<4, 4><<<dim3(64, 4), 320, 0, stream>>>(gat, fgw, pbuf, B_, HID_, HID_);
  k_red<4><<<300, 256, 0, stream>>>(pbuf, fgb, xcat, B_, HID_, 2 * HID_, 1);
  gemm_skp<4, 4><<<dim3(64, 4), 320, 0, stream>>>(fpn2, ffw, pbuf, B_, HID_, HID_);
  k_red<4><<<300, 256, 0, stream>>>(pbuf, ffb, xcat + 300, B_, HID_, 2 * HID_, 1);
  gemm_skp<4, 4><<<dim3(64, 4), 320, 0, stream>>>(xcat, w1, pbuf, B_, 2 * HID_, HID_);
  k_red<4><<<300, 256, 0, stream>>>(pbuf, b1, yb, B_, HID_, HID_, 1);
  k_final<<<64, 256, 0, stream>>>(yb, w2, b2, out);
}

// Round 6
// 693.585 us; speedup vs baseline: 3.1171x; 1.0447x over previous
//
#include <hip/hip_runtime.h>
#include <math.h>

// Problem constants
#define B_    256
#define N_    128
#define F_    133
#define H_    8
#define ND_   64     // NHID
#define HID_  300
#define FPD_  1489
#define FP2_  512
#define ALPHA_ 0.2f
#define NEG_  -9.0e15f

__device__ __forceinline__ float wred_sum(float v) {
#pragma unroll
  for (int m = 32; m >= 1; m >>= 1) v += __shfl_xor(v, m, 64);
  return v;
}
__device__ __forceinline__ float wred_max(float v) {
#pragma unroll
  for (int m = 32; m >= 1; m >>= 1) v = fmaxf(v, __shfl_xor(v, m, 64));
  return v;
}
__device__ __forceinline__ float lrelu(float x) { return x > 0.f ? x : ALPHA_ * x; }
__device__ __forceinline__ float eluf(float x)  { return x > 0.f ? x : expf(x) - 1.f; }
__device__ __forceinline__ float rdlane(float v, int l) {
  return __int_as_float(__builtin_amdgcn_readlane(__float_as_int(v), l));
}
// 16B load at 4B alignment (safe form)
__device__ __forceinline__ float4 ld4u(const float* p) {
  float4 v;
  __builtin_memcpy(&v, p, 16);
  return v;
}

// K1: Wh[b,h,n,d] = sum_f A[b,n,f] * W[h,f,d];  s/d projections fused.
// grid 2048, block 512 (8 waves; wave w = head h, lane = d). 16 rows/block.
__global__ __launch_bounds__(512) void k1_wh(
    const float* __restrict__ A, const float* __restrict__ W,
    const float* __restrict__ ah, float* __restrict__ Wh,
    float* __restrict__ sb, float* __restrict__ db) {
  __shared__ __align__(16) float As[16 * 136];  // ld=136 -> 16B-aligned chunks
  const int tid = threadIdx.x;
  const int lane = tid & 63;
  const int h = tid >> 6;
  const int m0 = blockIdx.x * 16;           // flat row b*N+n
  {
    const int r = tid >> 5;                 // 16 rows x 32 threads
    const int f0 = tid & 31;
    for (int f = f0; f < F_; f += 32)
      As[r * 136 + f] = A[(size_t)(m0 + r) * F_ + f];
  }
  __syncthreads();
  const float* Wg = W + (size_t)h * F_ * ND_;
  float acc[16];
#pragma unroll
  for (int r = 0; r < 16; ++r) acc[r] = 0.f;
  int f = 0;
  for (; f + 3 < F_; f += 4) {
    const float wv0 = Wg[(f + 0) * ND_ + lane];
    const float wv1 = Wg[(f + 1) * ND_ + lane];
    const float wv2 = Wg[(f + 2) * ND_ + lane];
    const float wv3 = Wg[(f + 3) * ND_ + lane];
#pragma unroll
    for (int r = 0; r < 16; ++r) {
      float4 a = *reinterpret_cast<const float4*>(&As[r * 136 + f]);
      acc[r] = fmaf(a.x, wv0, acc[r]);
      acc[r] = fmaf(a.y, wv1, acc[r]);
      acc[r] = fmaf(a.z, wv2, acc[r]);
      acc[r] = fmaf(a.w, wv3, acc[r]);
    }
  }
  for (; f < F_; ++f) {
    const float wv = Wg[f * ND_ + lane];
#pragma unroll
    for (int r = 0; r < 16; ++r)
      acc[r] = fmaf(As[r * 136 + f], wv, acc[r]);
  }
  float a1 = ah[h * 2 * ND_ + lane];
  float a2 = ah[h * 2 * ND_ + ND_ + lane];
  const int b = m0 >> 7, n0 = m0 & (N_ - 1);
  const size_t bh = (size_t)b * H_ + h;
#pragma unroll
  for (int r = 0; r < 16; ++r) {
    Wh[(bh * N_ + n0 + r) * ND_ + lane] = acc[r];
    float sv = wred_sum(acc[r] * a1);
    float dv = wred_sum(acc[r] * a2);
    if (lane == 0) {
      sb[bh * N_ + n0 + r] = sv;
      db[bh * N_ + n0 + r] = dv;
    }
  }
}

// K2: masked softmax over j + h = elu(attn @ Wh), written as hbuf[b,i,h*64+d].
__global__ __launch_bounds__(256) void k2_attn1(
    const float* __restrict__ Wh, const float* __restrict__ sb,
    const float* __restrict__ db, const int* __restrict__ adj,
    float* __restrict__ hb) {
  const int lane = threadIdx.x & 63;
  const int w = blockIdx.x * 4 + (threadIdx.x >> 6);  // 0..32767
  const int bh = w >> 4;
  const int i0 = (w & 15) * 8;
  const int b = bh >> 3, h = bh & 7;
  const float* dbase = db + (size_t)bh * N_;
  const float dv0 = dbase[lane], dv1 = dbase[64 + lane];
  float p0[8], p1[8];
#pragma unroll
  for (int r = 0; r < 8; ++r) {
    const int i = i0 + r;
    float sv = sb[(size_t)bh * N_ + i];
    const int* arow = adj + ((size_t)b * N_ + i) * N_;
    int a0 = arow[lane], a1i = arow[64 + lane];
    float e0 = a0 > 0 ? lrelu(sv + dv0) : NEG_;
    float e1 = a1i > 0 ? lrelu(sv + dv1) : NEG_;
    float mx = wred_max(fmaxf(e0, e1));
    float x0 = expf(e0 - mx), x1 = expf(e1 - mx);
    float inv = 1.f / wred_sum(x0 + x1);
    p0[r] = x0 * inv;
    p1[r] = x1 * inv;
  }
  const float* whb = Wh + (size_t)bh * N_ * ND_ + lane;
  float acc[8];
#pragma unroll
  for (int r = 0; r < 8; ++r) acc[r] = 0.f;
  for (int j = 0; j < 64; ++j) {
    float wv = whb[(size_t)j * ND_];
#pragma unroll
    for (int r = 0; r < 8; ++r) acc[r] = fmaf(rdlane(p0[r], j), wv, acc[r]);
  }
  for (int j = 0; j < 64; ++j) {
    float wv = whb[(size_t)(64 + j) * ND_];
#pragma unroll
    for (int r = 0; r < 8; ++r) acc[r] = fmaf(rdlane(p1[r], j), wv, acc[r]);
  }
  float* hrow = hb + ((size_t)b * N_ + i0) * (H_ * ND_) + h * ND_ + lane;
#pragma unroll
  for (int r = 0; r < 8; ++r) hrow[(size_t)r * (H_ * ND_)] = eluf(acc[r]);
}

// Tiled big-M GEMM: C[m,c] = act(sum_k A[m,k]*B[k,c]), N=300.
// Block: 64 rows x 300 cols; 320 threads = 8 row-groups x 40 col-threads.
// Thread tile: 8 rows x 8 contiguous cols -> per 4-k chunk: 8 ds_read_b128
// + 8 B float4 (L2) + 256 FMA (LDS:FMA instr ratio 0.031, was 0.25).
// k ascends per output element -> bitwise-stable vs previous rounds.
template <int K, int BK, int ACT, bool BATB>
__global__ __launch_bounds__(320) void gemm_t(
    const float* __restrict__ A, const float* __restrict__ Bm,
    float* __restrict__ C) {
  __shared__ __align__(16) float As[64 * BK];
  const int tid = threadIdx.x;
  const int c = tid % 40;           // col-thread
  const int rg = tid / 40;          // row-group (0..7)
  const int m0 = blockIdx.x * 64;
  const int col0 = c * 8;
  const bool g0 = (col0 + 3) < HID_;   // cols col0..col0+3 valid
  const bool g1 = (col0 + 7) < HID_;   // cols col0+4..col0+7 valid
  const float* Bp = BATB ? Bm + (size_t)(m0 >> 7) * K * HID_ : Bm;
  float acc[8][8];
#pragma unroll
  for (int r = 0; r < 8; ++r)
#pragma unroll
    for (int j = 0; j < 8; ++j) acc[r][j] = 0.f;

  for (int k0 = 0; k0 < K; k0 += BK) {
    __syncthreads();
    for (int idx = tid * 4; idx < 64 * BK; idx += 320 * 4) {
      const int r = idx / BK, kk = idx % BK;
      *reinterpret_cast<float4*>(&As[idx]) =
          *reinterpret_cast<const float4*>(A + (size_t)(m0 + r) * K + k0 + kk);
    }
    __syncthreads();
    for (int k = 0; k < BK; k += 4) {
      float4 a4[8];
#pragma unroll
      for (int r = 0; r < 8; ++r)
        a4[r] = *reinterpret_cast<const float4*>(&As[(rg * 8 + r) * BK + k]);
      float bq[4][8];
#pragma unroll
      for (int kk = 0; kk < 4; ++kk) {
        const float* brow = Bp + (size_t)(k0 + k + kk) * HID_ + col0;
        float4 b0 = g0 ? *reinterpret_cast<const float4*>(brow)
                       : float4{0, 0, 0, 0};
        float4 b1 = g1 ? *reinterpret_cast<const float4*>(brow + 4)
                       : float4{0, 0, 0, 0};
        bq[kk][0] = b0.x; bq[kk][1] = b0.y; bq[kk][2] = b0.z; bq[kk][3] = b0.w;
        bq[kk][4] = b1.x; bq[kk][5] = b1.y; bq[kk][6] = b1.z; bq[kk][7] = b1.w;
      }
#pragma unroll
      for (int kk = 0; kk < 4; ++kk) {
#pragma unroll
        for (int r = 0; r < 8; ++r) {
          const float av = (kk == 0) ? a4[r].x : (kk == 1) ? a4[r].y
                         : (kk == 2) ? a4[r].z : a4[r].w;
#pragma unroll
          for (int j = 0; j < 8; ++j)
            acc[r][j] = fmaf(av, bq[kk][j], acc[r][j]);
        }
      }
    }
  }
#pragma unroll
  for (int r = 0; r < 8; ++r) {
    float o[8];
#pragma unroll
    for (int j = 0; j < 8; ++j)
      o[j] = (ACT == 2) ? eluf(acc[r][j]) : acc[r][j];
    float* crow = C + (size_t)(m0 + rg * 8 + r) * HID_ + col0;
    if (g0) {
      float4 v = {o[0], o[1], o[2], o[3]};
      *reinterpret_cast<float4*>(crow) = v;
    }
    if (g1) {
      float4 v = {o[4], o[5], o[6], o[7]};
      *reinterpret_cast<float4*>(crow + 4) = v;
    }
  }
}

// Split-K partial GEMM for small-M matmuls: grid (M/ROWS, KSPLIT).
template <int ROWS, int KSPLIT>
__global__ void gemm_skp(const float* __restrict__ A, const float* __restrict__ Bm,
                         float* __restrict__ P, int M, int K, int N) {
  const int c = threadIdx.x;
  const int r0 = blockIdx.x * ROWS;
  const int ks = blockIdx.y;
  if (c >= N) return;
  const int kchunk = (K + KSPLIT - 1) / KSPLIT;
  const int k0 = ks * kchunk;
  const int k1 = (k0 + kchunk < K) ? (k0 + kchunk) : K;
  float acc[ROWS];
#pragma unroll
  for (int r = 0; r < ROWS; ++r) acc[r] = 0.f;
  int k = k0;
  for (; k + 3 < k1; k += 4) {
    const float b0 = Bm[(size_t)(k + 0) * N + c];
    const float b1 = Bm[(size_t)(k + 1) * N + c];
    const float b2 = Bm[(size_t)(k + 2) * N + c];
    const float b3 = Bm[(size_t)(k + 3) * N + c];
#pragma unroll
    for (int r = 0; r < ROWS; ++r) {
      float4 a = ld4u(A + (size_t)(r0 + r) * K + k);
      acc[r] = fmaf(a.x, b0, acc[r]);
      acc[r] = fmaf(a.y, b1, acc[r]);
      acc[r] = fmaf(a.z, b2, acc[r]);
      acc[r] = fmaf(a.w, b3, acc[r]);
    }
  }
  for (; k < k1; ++k) {
    const float bv = Bm[(size_t)k * N + c];
#pragma unroll
    for (int r = 0; r < ROWS; ++r)
      acc[r] = fmaf(A[(size_t)(r0 + r) * K + k], bv, acc[r]);
  }
#pragma unroll
  for (int r = 0; r < ROWS; ++r)
    P[((size_t)ks * M + r0 + r) * N + c] = acc[r];
}

// Reduce split-K partials + bias + act. act: 0 none, 1 relu.
template <int KSPLIT>
__global__ void k_red(const float* __restrict__ P, const float* __restrict__ bias,
                      float* __restrict__ C, int M, int N, int ldc, int act) {
  const int idx = blockIdx.x * 256 + threadIdx.x;
  if (idx >= M * N) return;
  const int m = idx / N, c = idx - m * N;
  float v = 0.f;
#pragma unroll
  for (int p = 0; p < KSPLIT; ++p) v += P[(size_t)p * M * N + idx];
  if (bias) v += bias[c];
  if (act == 1) v = fmaxf(v, 0.f);
  C[(size_t)m * ldc + c] = v;
}

// K4: s2/d2 = Wh2 @ a_out halves. One wave per row.
__global__ __launch_bounds__(256) void k4_sd2(
    const float* __restrict__ Wh2, const float* __restrict__ ao,
    float* __restrict__ s2, float* __restrict__ d2) {
  const int lane = threadIdx.x & 63;
  const int row = blockIdx.x * 4 + (threadIdx.x >> 6);
  const float* wrow = Wh2 + (size_t)row * HID_;
  float as = 0.f, ad = 0.f;
  for (int c = lane; c < HID_; c += 64) {
    float v = wrow[c];
    as = fmaf(v, ao[c], as);
    ad = fmaf(v, ao[HID_ + c], ad);
  }
  as = wred_sum(as);
  ad = wred_sum(ad);
  if (lane == 0) { s2[row] = as; d2[row] = ad; }
}

// K5: attn2 probabilities p2[b,i,j]. One wave per row i.
__global__ __launch_bounds__(256) void k5_p2(
    const float* __restrict__ s2, const float* __restrict__ d2,
    const int* __restrict__ adj, float* __restrict__ p2) {
  const int lane = threadIdx.x & 63;
  const int row = blockIdx.x * 4 + (threadIdx.x >> 6);  // b*N+i
  const int b = row >> 7;
  float sv = s2[row];
  const float* drow = d2 + (size_t)b * N_;
  const int* arow = adj + (size_t)row * N_;
  float dv0 = drow[lane], dv1 = drow[64 + lane];
  int a0 = arow[lane], a1i = arow[64 + lane];
  float e0 = a0 > 0 ? lrelu(sv + dv0) : NEG_;
  float e1 = a1i > 0 ? lrelu(sv + dv1) : NEG_;
  float mx = wred_max(fmaxf(e0, e1));
  float x0 = expf(e0 - mx), x1 = expf(e1 - mx);
  float inv = 1.f / wred_sum(x0 + x1);
  p2[(size_t)row * N_ + lane] = x0 * inv;
  p2[(size_t)row * N_ + 64 + lane] = x1 * inv;
}

// K7: per-row max and log-sum-exp over 300 cols. One wave per row.
__global__ __launch_bounds__(256) void k7_lse(
    const float* __restrict__ ob, float* __restrict__ mx, float* __restrict__ ls) {
  const int lane = threadIdx.x & 63;
  const int row = blockIdx.x * 4 + (threadIdx.x >> 6);
  const float* orow = ob + (size_t)row * HID_;
  float v[5], m = -1e30f;
#pragma unroll
  for (int q = 0; q < 5; ++q) {
    int c = lane + q * 64;
    v[q] = (c < HID_) ? orow[c] : -1e30f;
    m = fmaxf(m, v[q]);
  }
  m = wred_max(m);
  float s = 0.f;
#pragma unroll
  for (int q = 0; q < 5; ++q) {
    int c = lane + q * 64;
    if (c < HID_) s += expf(v[q] - m);
  }
  s = wred_sum(s);
  if (lane == 0) { mx[row] = m; ls[row] = logf(s); }
}

// K8: gat_out[b,c] = mean_i (ob[b,i,c] - mx - ls). grid 256, block 320.
__global__ void k8_mean(const float* __restrict__ ob, const float* __restrict__ mx,
                        const float* __restrict__ ls, float* __restrict__ gat) {
  const int c = threadIdx.x;
  const int b = blockIdx.x;
  if (c >= HID_) return;
  float acc = 0.f;
  for (int i = 0; i < N_; ++i) {
    int row = b * N_ + i;
    acc += ob[(size_t)row * HID_ + c] - mx[row] - ls[row];
  }
  gat[(size_t)b * HID_ + c] = acc * (1.f / N_);
}

// out[b] = sigmoid(y[b,:] @ ffn_w2 + b2). One wave per row.
__global__ __launch_bounds__(256) void k_final(
    const float* __restrict__ y, const float* __restrict__ w2,
    const float* __restrict__ b2, float* __restrict__ out) {
  const int lane = threadIdx.x & 63;
  const int b = blockIdx.x * 4 + (threadIdx.x >> 6);
  float acc = 0.f;
  for (int c = lane; c < HID_; c += 64)
    acc = fmaf(y[(size_t)b * HID_ + c], w2[c], acc);
  acc = wred_sum(acc);
  if (lane == 0) out[b] = 1.f / (1.f + expf(-(acc + b2[0])));
}

extern "C" void kernel_launch(void* const* d_in, const int* in_sizes, int n_in,
                              void* d_out, int out_size, void* d_ws, size_t ws_size,
                              hipStream_t stream) {
  const float* atom  = (const float*)d_in[0];
  const float* fp    = (const float*)d_in[1];
  const float* Whead = (const float*)d_in[2];
  const float* ah    = (const float*)d_in[3];
  const float* Wout  = (const float*)d_in[4];
  const float* aout  = (const float*)d_in[5];
  const float* fc1w  = (const float*)d_in[6];
  const float* fc1b  = (const float*)d_in[7];
  const float* fc2w  = (const float*)d_in[8];
  const float* fc2b  = (const float*)d_in[9];
  const float* fgw   = (const float*)d_in[10];
  const float* fgb   = (const float*)d_in[11];
  const float* ffw   = (const float*)d_in[12];
  const float* ffb   = (const float*)d_in[13];
  const float* w1    = (const float*)d_in[14];
  const float* b1    = (const float*)d_in[15];
  const float* w2    = (const float*)d_in[16];
  const float* b2    = (const float*)d_in[17];
  const int*   adj   = (const int*)d_in[18];
  float* out = (float*)d_out;

  float* ws = (float*)d_ws;
  // Aliased layout (peak ~139 MB of floats):
  float* Wh   = ws;                       // 16,777,216   [K1 w, K2 r]
  float* Wh2  = ws;                       //  9,830,400   [K3 w .. K6 r]  (Wh dead)
  float* pbuf = ws;                       // <=1,048,576  [split-K partials; only
                                          //  live before k1 and after k8]
  float* p2   = ws + 9830400;             //  4,194,304   [K5 w, K6 r]
  float* sb   = ws + 16777216;            //    262,144
  float* db   = ws + 17039360;            //    262,144
  float* hb   = ws + 17301504;            // 16,777,216   [K2 w, K3 r]
  float* ob   = ws + 17301504;            //  9,830,400   [K6 w ..]  (hb dead)
  float* s2   = ws + 34078720;
  float* d2   = s2 + 32768;
  float* mxb  = d2 + 32768;
  float* lsb  = mxb + 32768;
  float* gat  = lsb + 32768;              //  76,800
  float* fpn1 = gat + 76800;              // 131,072
  float* fpn2 = fpn1 + 131072;            //  76,800
  float* xcat = fpn2 + 76800;             // 153,600
  float* yb   = xcat + 153600;            //  76,800

  // FPN branch (before k1 so pbuf aliasing of Wh region is safe)
  gemm_skp<4, 8><<<dim3(64, 8), 512, 0, stream>>>(fp, fc1w, pbuf, B_, FPD_, FP2_);
  k_red<8><<<512, 256, 0, stream>>>(pbuf, fc1b, fpn1, B_, FP2_, FP2_, 1);
  gemm_skp<4, 4><<<dim3(64, 4), 320, 0, stream>>>(fpn1, fc2w, pbuf, B_, FP2_, HID_);
  k_red<4><<<300, 256, 0, stream>>>(pbuf, fc2b, fpn2, B_, HID_, HID_, 0);

  // GAT stage 1
  k1_wh<<<2048, 512, 0, stream>>>(atom, Whead, ah, Wh, sb, db);
  k2_attn1<<<8192, 256, 0, stream>>>(Wh, sb, db, adj, hb);

  // Wh2 = h @ W_out  (M=32768, K=512, N=300)
  gemm_t<512, 128, 0, false><<<512, 320, 0, stream>>>(hb, Wout, Wh2);

  // GAT stage 2
  k4_sd2<<<8192, 256, 0, stream>>>(Wh2, aout, s2, d2);
  k5_p2<<<8192, 256, 0, stream>>>(s2, d2, adj, p2);
  // ob = elu(p2 @ Wh2)  (M=32768, K=128, N=300, B batched per 128 rows)
  gemm_t<128, 128, 2, true><<<512, 320, 0, stream>>>(p2, Wh2, ob);
  k7_lse<<<8192, 256, 0, stream>>>(ob, mxb, lsb);
  k8_mean<<<256, 320, 0, stream>>>(ob, mxb, lsb, gat);

  // Head (after k8: entire low ws region dead -> pbuf reuse is safe)
  gemm_skp<4, 4><<<dim3(64, 4), 320, 0, stream>>>(gat, fgw, pbuf, B_, HID_, HID_);
  k_red<4><<<300, 256, 0, stream>>>(pbuf, fgb, xcat, B_, HID_, 2 * HID_, 1);
  gemm_skp<4, 4><<<dim3(64, 4), 320, 0, stream>>>(fpn2, ffw, pbuf, B_, HID_, HID_);
  k_red<4><<<300, 256, 0, stream>>>(pbuf, ffb, xcat + 300, B_, HID_, 2 * HID_, 1);
  gemm_skp<4, 4><<<dim3(64, 4), 320, 0, stream>>>(xcat, w1, pbuf, B_, 2 * HID_, HID_);
  k_red<4><<<300, 256, 0, stream>>>(pbuf, b1, yb, B_, HID_, HID_, 1);
  k_final<<<64, 256, 0, stream>>>(yb, w2, b2, out);
}